// Round 2
// baseline (322.383 us; speedup 1.0000x reference)
//
#include <hip/hip_runtime.h>

// iRPE contextual/transposed PRODUCT, round-7: two-kernel split.
//
//   lt[bh,i,k] = sum_d x[bh,i,d] * W[h,d,k]     (12.8 MB, kernel 1 -> ws)
//   out[bh,i,j] = lt[bh,i, bucket(i,j)]          (256 MiB, kernel 2)
//
// r5/r6 post-mortem: two different store decompositions both land ~135-140 us
// device time (~2 TB/s effective) => store address pattern is NOT the
// bottleneck. The fused structure is: each block interleaves a VMEM-heavy
// GEMV (128 scalar W loads/wave + per-d LDS reads + serial fma chains)
// between two barriers before its store burst, so the store pipe runs at
// ~30% duty cycle and VMEM issue is shared between W-load clog and drain.
// Fix: materialize lt once (tiny), then a second kernel that is ~95% pure
// streaming stores: 3.3 KB lt load + arithmetic buckets + 64 KB nt stores.
//
// bucket(i,j) computed arithmetically (verified absmax 0.0 in r6): for
// alpha=1.9 beta=3.8 gamma=15.2, pidx(d) = sign(d)*q(|d|),
// q = {0,1,2,2,3,3,...}; bucket = (pidx(dy)+3)*7 + (pidx(dx)+3).

constexpr int cL   = 1024;
constexpr int cD   = 64;
constexpr int cK   = 49;
constexpr int cKP  = 52;   // padded k-stride in ws (rows 16B-aligned)
constexpr int cIT1 = 32;   // i rows per block, kernel 1
constexpr int cIT2 = 16;   // i rows per block, kernel 2 (16-run shares yi)

typedef float vf4 __attribute__((ext_vector_type(4)));

// piecewise_index(d) + BETA_INT for this config
__device__ __forceinline__ int bucket_c(int d) {
    int a = d < 0 ? -d : d;
    int m = a < 4 ? a : 4;     // min(|d|,4)
    m -= (m >= 3) ? 1 : 0;     // q(|d|) = {0,1,2,2,3,3,...}
    int p = d < 0 ? -m : m;
    return p + 3;
}

// ---- kernel 1: lt GEMV into workspace --------------------------------
__global__ __launch_bounds__(256) void irpe_lt(
    const float* __restrict__ x,   // (bh, i, d)
    const float* __restrict__ W,   // (h, d, k)
    float*       __restrict__ ws)  // (bh, i, 52) padded lt
{
    __shared__ float xs[cIT1 * cD];          // 8 KB

    const int gid = blockIdx.x;
    const int bh  = gid & 63;
    const int it  = gid >> 6;                // 0..31
    const int i0  = it * cIT1;
    const int h   = bh & 7;
    const int tid = threadIdx.x;

    // stage x tile: one contiguous 8 KB span
    const vf4* x4  = (const vf4*)(x + ((size_t)bh * cL + i0) * cD);
    vf4*       xs4 = (vf4*)xs;
    xs4[tid]       = x4[tid];
    xs4[tid + 256] = x4[tid + 256];
    __syncthreads();

    // lt: same fmaf d-ascending chain as r5/r6 -> bitwise-identical values.
    // Consecutive lanes -> consecutive k => coalesced W loads (L1-resident).
    float* wsrow = ws + ((size_t)bh * cL + i0) * cKP;
    for (int p = tid; p < cIT1 * cK; p += 256) {
        const int li = p / cK;
        const int k  = p - li * cK;
        const float* wp = W + (size_t)h * cD * cK + k;
        const float* xr = xs + li * cD;
        float acc = 0.0f;
        #pragma unroll
        for (int d = 0; d < cD; ++d) {
            acc = fmaf(xr[d], wp[(size_t)d * cK], acc);
        }
        wsrow[(size_t)li * cKP + k] = acc;
    }
}

// ---- kernel 2: arithmetic-bucket gather + pure streaming stores ------
__global__ __launch_bounds__(256) void irpe_gather(
    const float* __restrict__ ws,  // (bh, i, 52) padded lt
    float*       __restrict__ out) // (bh, i, j)
{
    __shared__ float lts[cIT2][cKP];         // 3.3 KB

    const int gid = blockIdx.x;
    const int bh  = gid & 63;
    const int it  = gid >> 6;                // 0..63
    const int i0  = it * cIT2;
    const int tid = threadIdx.x;

    // lt tile: 208 x float4 = 3.3 KB (plain loads: may still be L2-hot)
    if (tid < cIT2 * (cKP / 4)) {
        ((vf4*)lts)[tid] =
            ((const vf4*)ws)[((size_t)bh * cL + i0) * (cKP / 4) + tid];
    }

    // buckets, fully arithmetic. i0 is 16-aligned => all 16 rows share yi.
    const int j0   = tid * 4;                // this thread's 4 consecutive j
    const int xj   = j0 & 31;
    const int yj   = j0 >> 5;
    const int yi   = i0 >> 5;
    const int xi0  = i0 & 31;                // 0 or 16
    const int rbase = 7 * bucket_c(yi - yj);
    const int base  = xi0 - xj;
    // dx = base + il - cc, il in [0,16), cc in [0,4) -> t = il-cc+3 in [0,19)
    int cv[cIT2 + 3];
    #pragma unroll
    for (int t = 0; t < cIT2 + 3; ++t)
        cv[t] = rbase + bucket_c(base + t - 3);

    __syncthreads();

    // 16 rows x 4 KB = one contiguous 64 KB nt-store span per block
    vf4* obase = (vf4*)(out + ((size_t)bh * cL + i0) * cL);
    #pragma unroll
    for (int il = 0; il < cIT2; ++il) {
        const float* lrow = lts[il];
        vf4 o;
        o.x = lrow[cv[il + 3]];              // cc = 0
        o.y = lrow[cv[il + 2]];              // cc = 1
        o.z = lrow[cv[il + 1]];              // cc = 2
        o.w = lrow[cv[il + 0]];              // cc = 3
        __builtin_nontemporal_store(o, &obase[(size_t)il * (cL / 4) + tid]);
    }
}

// ---- fallback: r6 fused single-kernel (if ws too small) --------------
__global__ __launch_bounds__(256) void irpe_fused(
    const float* __restrict__ x,
    const float* __restrict__ W,
    float*       __restrict__ out)
{
    __shared__ vf4   xs4[8][cD / 4];
    __shared__ float lts[8 * cK];

    const int gid = blockIdx.x;
    const int bh  = gid & 63;
    const int it  = gid >> 6;
    const int i0  = it * 8;
    const int h   = bh & 7;
    const int tid = threadIdx.x;

    if (tid < 8 * (cD / 4)) {
        const int li = tid >> 4;
        const int dq = tid & 15;
        xs4[li][dq] = __builtin_nontemporal_load(
            &((const vf4*)x)[((size_t)bh * cL + (i0 + li)) * (cD / 4) + dq]);
    }
    __syncthreads();

    for (int p = tid; p < 8 * cK; p += 256) {
        const int li = p / cK;
        const int k  = p - li * cK;
        const float* wp = W + (size_t)h * cD * cK + k;
        const float* xr = (const float*)&xs4[li][0];
        float acc = 0.0f;
        #pragma unroll
        for (int d = 0; d < cD; ++d) acc = fmaf(xr[d], wp[(size_t)d * cK], acc);
        lts[p] = acc;
    }
    __syncthreads();

    const int j0   = tid * 4;
    const int xj   = j0 & 31;
    const int yj   = j0 >> 5;
    const int yi   = i0 >> 5;
    const int xi0  = i0 & 31;
    const int rbase = 7 * bucket_c(yi - yj);
    const int base  = xi0 - xj;
    int cv[11];
    #pragma unroll
    for (int t = 0; t < 11; ++t) cv[t] = rbase + bucket_c(base + t - 3);

    vf4* obase = (vf4*)(out + ((size_t)bh * cL + i0) * cL);
    #pragma unroll
    for (int il = 0; il < 8; ++il) {
        const float* lrow = lts + il * cK;
        vf4 o;
        o.x = lrow[cv[il + 3]];
        o.y = lrow[cv[il + 2]];
        o.z = lrow[cv[il + 1]];
        o.w = lrow[cv[il + 0]];
        __builtin_nontemporal_store(o, &obase[(size_t)il * (cL / 4) + tid]);
    }
}

extern "C" void kernel_launch(void* const* d_in, const int* in_sizes, int n_in,
                              void* d_out, int out_size, void* d_ws, size_t ws_size,
                              hipStream_t stream) {
    const float* x   = (const float*)d_in[0];   // (8,8,1024,64) fp32
    const float* W   = (const float*)d_in[1];   // (8,64,49) fp32
    float*       out = (float*)d_out;           // (8,8,1024,1024) fp32

    const size_t ws_need = (size_t)64 * cL * cKP * sizeof(float); // 13.6 MB
    if (ws_size >= ws_need && d_ws != nullptr) {
        irpe_lt<<<64 * (cL / cIT1), 256, 0, stream>>>(x, W, (float*)d_ws);
        irpe_gather<<<64 * (cL / cIT2), 256, 0, stream>>>((const float*)d_ws, out);
    } else {
        irpe_fused<<<64 * (cL / 8), 256, 0, stream>>>(x, W, out);
    }
}